// Round 1
// baseline (434.420 us; speedup 1.0000x reference)
//
#include <hip/hip_runtime.h>
#include <stdint.h>

#define IN_F 2048
#define OUT_F 2048
#define MTOK 16384   // 4 * 4096 tokens

typedef __attribute__((ext_vector_type(8))) __bf16 bf16x8;
typedef __attribute__((ext_vector_type(4))) float f32x4;
typedef __attribute__((ext_vector_type(4))) unsigned short us4;

typedef const __attribute__((address_space(1))) void g_void;
typedef __attribute__((address_space(3))) void l_void;

// 16B async global->LDS. LDS dest must be wave-uniform base + lane*16.
__device__ __forceinline__ void async16(void* lds, const void* g) {
    __builtin_amdgcn_global_load_lds((g_void*)(uintptr_t)g, (l_void*)(uintptr_t)lds, 16, 0, 0);
}

// fp32 -> bf16 round-to-nearest-even
__device__ __forceinline__ unsigned short f2bf(float x) {
    union { float f; uint32_t u; } v; v.f = x;
    uint32_t r = v.u + 0x7fffu + ((v.u >> 16) & 1u);
    return (unsigned short)(r >> 16);
}

// ---------------------------------------------------------------------------
// K0a: Bp[o][j] = bf16(mix_w[o][ ((j&31)<<6) | (j>>5) ])
// Folds the reference _shuffle into the mix weight columns so stage1 output
// feeds the GEMM directly (coalesced). One block per row o.
// ---------------------------------------------------------------------------
__global__ void k_permute_mixw(const float* __restrict__ W, unsigned short* __restrict__ Bp) {
    __shared__ float row[2112];  // 2048 + pad every 32
    const int t = threadIdx.x;
    const float* src = W + (size_t)blockIdx.x * IN_F;
#pragma unroll
    for (int q = 0; q < 2; ++q) {
        int id4 = q * 256 + t;
        float4 v = *(const float4*)(src + id4 * 4);
        int i = id4 * 4;
        int b = i + (i >> 5);
        row[b] = v.x; row[b + 1] = v.y; row[b + 2] = v.z; row[b + 3] = v.w;
    }
    __syncthreads();
    unsigned short* dst = Bp + (size_t)blockIdx.x * IN_F;
#pragma unroll
    for (int q = 0; q < 8; ++q) {
        int j = q * 256 + t;
        int i = ((j & 31) << 6) | (j >> 5);
        dst[j] = f2bf(row[i + (i >> 5)]);
    }
}

// ---------------------------------------------------------------------------
// K0b: W1T/W2T[g][d][c] = bf16(stage[g*64+c][d])  (transposed -> B-operand
// fragments become contiguous 16B reads). Blocks 0..31 -> stage1, 32..63 -> stage2.
// ---------------------------------------------------------------------------
__global__ void k_transpose_stages(const float* __restrict__ s1, const float* __restrict__ s2,
                                   unsigned short* __restrict__ W1T, unsigned short* __restrict__ W2T) {
    __shared__ float tile[64 * 65];  // pad leading dim -> conflict-free transpose
    const int b = blockIdx.x;
    const float* src = (b < 32 ? s1 : s2) + (size_t)(b & 31) * 4096;
    unsigned short* dst = (b < 32 ? W1T : W2T) + (size_t)(b & 31) * 4096;
    const int t = threadIdx.x;
#pragma unroll
    for (int q = 0; q < 16; ++q) {
        int id = q * 256 + t;                  // src row-major [c][d]
        tile[(id >> 6) * 65 + (id & 63)] = src[id];
    }
    __syncthreads();
#pragma unroll
    for (int q = 0; q < 16; ++q) {
        int id = q * 256 + t;                  // dst row-major [d][c]
        int d = id >> 6, c = id & 63;
        dst[id] = f2bf(tile[c * 65 + d]);
    }
}

// ---------------------------------------------------------------------------
// K1: stage1 block-diagonal GEMM.  hA[m][g*64+d] = sum_c x[m][g*64+c]*W1[g][c][d]
// 128 tokens x one group per block. x fp32 -> bf16 in regs -> LDS; MFMA 16x16x32.
// ---------------------------------------------------------------------------
__global__ __launch_bounds__(256, 2) void k_stage1(
    const float* __restrict__ X, const unsigned short* __restrict__ W1T,
    unsigned short* __restrict__ H) {
    __shared__ unsigned short smem[128 * 64 + 64 * 64];  // Xs 16KB + Ws 8KB
    unsigned short* Xs = smem;
    unsigned short* Ws = smem + 128 * 64;
    const int t = threadIdx.x;
    const int lane = t & 63, wave = t >> 6;
    const int quad = lane >> 4, l16 = lane & 15;
    const int m0 = blockIdx.x * 128;
    const int g = blockIdx.y;

    const unsigned short* Wg = W1T + g * 4096;
    async16((char*)Ws + t * 16, Wg + t * 8);
    async16((char*)Ws + 4096 + t * 16, Wg + 2048 + t * 8);

    const float* Xg = X + (size_t)m0 * IN_F + g * 64;
#pragma unroll
    for (int q = 0; q < 8; ++q) {
        int id = q * 256 + t;                  // float4 chunk id
        int r = id >> 4, c4 = id & 15;
        float4 v = *(const float4*)(Xg + (size_t)r * IN_F + c4 * 4);
        us4 b; b.x = f2bf(v.x); b.y = f2bf(v.y); b.z = f2bf(v.z); b.w = f2bf(v.w);
        *(us4*)(Xs + r * 64 + c4 * 4) = b;
    }
    __syncthreads();

    f32x4 acc[2][4];
#pragma unroll
    for (int i = 0; i < 2; ++i)
#pragma unroll
        for (int j = 0; j < 4; ++j) acc[i][j] = (f32x4)0.f;

#pragma unroll
    for (int ks = 0; ks < 2; ++ks) {
        bf16x8 af[2], bfr[4];
#pragma unroll
        for (int i = 0; i < 2; ++i)
            af[i] = *(const bf16x8*)(Xs + (wave * 32 + i * 16 + l16) * 64 + ks * 32 + quad * 8);
#pragma unroll
        for (int j = 0; j < 4; ++j)
            bfr[j] = *(const bf16x8*)(Ws + (j * 16 + l16) * 64 + ks * 32 + quad * 8);
#pragma unroll
        for (int i = 0; i < 2; ++i)
#pragma unroll
            for (int j = 0; j < 4; ++j)
                acc[i][j] = __builtin_amdgcn_mfma_f32_16x16x32_bf16(af[i], bfr[j], acc[i][j], 0, 0, 0);
    }

    // C/D layout: row = quad*4 + r, col = l16 (verified m89/m91)
#pragma unroll
    for (int i = 0; i < 2; ++i)
#pragma unroll
        for (int j = 0; j < 4; ++j)
#pragma unroll
            for (int r = 0; r < 4; ++r) {
                int m = m0 + wave * 32 + i * 16 + quad * 4 + r;
                int col = g * 64 + j * 16 + l16;
                H[(size_t)m * IN_F + col] = f2bf(acc[i][j][r]);
            }
}

// ---------------------------------------------------------------------------
// K2: mix GEMM (M=16384, N=2048, K=2048, A & B both [rows][K] bf16, m97
// structure) with stage2 block-diagonal fused into the epilogue.
// ---------------------------------------------------------------------------
__global__ __launch_bounds__(256, 2) void k_mix_gemm(
    const unsigned short* __restrict__ A, const unsigned short* __restrict__ B,
    const unsigned short* __restrict__ W2T, float* __restrict__ C) {
    __shared__ unsigned short smem[16384];   // As 16KB | Bs 16KB
    unsigned short* As = smem;
    unsigned short* Bs = smem + 8192;
    const int t = threadIdx.x;
    const int lane = t & 63, wave = t >> 6;
    const int quad = lane >> 4, l16 = lane & 15;
    const int mw = wave & 1, nw = wave >> 1;
    const int m0 = blockIdx.x * 128;
    const int n0 = blockIdx.y * 128;
    const int rr = t >> 3, chunk = t & 7;   // 32 rows x 8 16B-chunks per issue

    f32x4 acc[4][4];
#pragma unroll
    for (int i = 0; i < 4; ++i)
#pragma unroll
        for (int j = 0; j < 4; ++j) acc[i][j] = (f32x4)0.f;

    for (int kb = 0; kb < IN_F; kb += 64) {
#pragma unroll
        for (int q = 0; q < 4; ++q) {
            int r = q * 32 + rr;
            async16((char*)As + (size_t)(q * 4096 + t * 16),
                    A + (size_t)(m0 + r) * IN_F + kb + chunk * 8);
            async16((char*)Bs + (size_t)(q * 4096 + t * 16),
                    B + (size_t)(n0 + r) * IN_F + kb + chunk * 8);
        }
        __syncthreads();
#pragma unroll
        for (int ks = 0; ks < 2; ++ks) {
            bf16x8 af[4], bfr[4];
#pragma unroll
            for (int i = 0; i < 4; ++i)
                af[i] = *(const bf16x8*)(As + (mw * 64 + i * 16 + l16) * 64 + ks * 32 + quad * 8);
#pragma unroll
            for (int j = 0; j < 4; ++j)
                bfr[j] = *(const bf16x8*)(Bs + (nw * 64 + j * 16 + l16) * 64 + ks * 32 + quad * 8);
#pragma unroll
            for (int i = 0; i < 4; ++i)
#pragma unroll
                for (int j = 0; j < 4; ++j)
                    acc[i][j] = __builtin_amdgcn_mfma_f32_16x16x32_bf16(af[i], bfr[j], acc[i][j], 0, 0, 0);
        }
        __syncthreads();
    }

    // ---- fused stage2 epilogue ----
    // Wave's 64x64 acc spans exactly one stage2 group g. Round-trip acc through
    // LDS (C/D layout -> A-operand layout, m120 pattern), then P @ W2_g.
    unsigned short* P = smem + wave * 4096;  // 8KB wave-private, reuses As/Bs
#pragma unroll
    for (int i = 0; i < 4; ++i)
#pragma unroll
        for (int j = 0; j < 4; ++j)
#pragma unroll
            for (int r = 0; r < 4; ++r)
                P[(i * 16 + quad * 4 + r) * 64 + j * 16 + l16] = f2bf(acc[i][j][r]);

    const int g = (n0 >> 6) + nw;
    const unsigned short* W2g = W2T + g * 4096;   // [d][c] bf16, L2-resident
    bf16x8 wb[4][2];
#pragma unroll
    for (int j = 0; j < 4; ++j)
#pragma unroll
        for (int ks = 0; ks < 2; ++ks)
            wb[j][ks] = *(const bf16x8*)(W2g + (j * 16 + l16) * 64 + ks * 32 + quad * 8);

#pragma unroll
    for (int i = 0; i < 4; ++i) {
        bf16x8 pa0 = *(const bf16x8*)(P + (i * 16 + l16) * 64 + quad * 8);
        bf16x8 pa1 = *(const bf16x8*)(P + (i * 16 + l16) * 64 + 32 + quad * 8);
#pragma unroll
        for (int j = 0; j < 4; ++j) {
            f32x4 o = (f32x4)0.f;
            o = __builtin_amdgcn_mfma_f32_16x16x32_bf16(pa0, wb[j][0], o, 0, 0, 0);
            o = __builtin_amdgcn_mfma_f32_16x16x32_bf16(pa1, wb[j][1], o, 0, 0, 0);
            float* Cp = C + (size_t)(m0 + mw * 64 + i * 16 + quad * 4) * OUT_F
                          + (n0 + nw * 64 + j * 16 + l16);
#pragma unroll
            for (int r = 0; r < 4; ++r) Cp[(size_t)r * OUT_F] = o[r];
        }
    }
}

// ---------------------------------------------------------------------------
extern "C" void kernel_launch(void* const* d_in, const int* in_sizes, int n_in,
                              void* d_out, int out_size, void* d_ws, size_t ws_size,
                              hipStream_t stream) {
    const float* x  = (const float*)d_in[0];
    const float* s1 = (const float*)d_in[1];
    const float* s2 = (const float*)d_in[2];
    const float* mw = (const float*)d_in[3];
    float* out = (float*)d_out;

    char* ws = (char*)d_ws;
    unsigned short* hA  = (unsigned short*)ws;                                   // 64 MB
    unsigned short* Bp  = (unsigned short*)(ws + (size_t)MTOK * IN_F * 2);       // 8 MB
    unsigned short* W1T = (unsigned short*)(ws + (size_t)MTOK * IN_F * 2
                                               + (size_t)OUT_F * IN_F * 2);      // 256 KB
    unsigned short* W2T = W1T + 32 * 4096;                                       // 256 KB

    k_permute_mixw<<<2048, 256, 0, stream>>>(mw, Bp);
    k_transpose_stages<<<64, 256, 0, stream>>>(s1, s2, W1T, W2T);
    k_stage1<<<dim3(128, 32), 256, 0, stream>>>(x, W1T, hA);
    k_mix_gemm<<<dim3(128, 16), 256, 0, stream>>>(hA, Bp, W2T, out);
}

// Round 2
// 399.930 us; speedup vs baseline: 1.0862x; 1.0862x over previous
//
#include <hip/hip_runtime.h>
#include <stdint.h>

#define IN_F 2048
#define OUT_F 2048
#define MTOK 16384   // 4 * 4096 tokens

typedef __attribute__((ext_vector_type(8))) __bf16 bf16x8;
typedef __attribute__((ext_vector_type(4))) float f32x4;
typedef __attribute__((ext_vector_type(4))) unsigned short us4;
typedef __attribute__((ext_vector_type(8))) unsigned short us8;

typedef const __attribute__((address_space(1))) void g_void;
typedef __attribute__((address_space(3))) void l_void;

// 16B async global->LDS. LDS dest is wave-uniform base + lane*16 (no padding
// possible on the LDS side -> we XOR-swizzle on the GLOBAL-source side).
__device__ __forceinline__ void async16(void* lds, const void* g) {
    __builtin_amdgcn_global_load_lds((g_void*)(uintptr_t)g, (l_void*)(uintptr_t)lds, 16, 0, 0);
}

// fp32 -> bf16 round-to-nearest-even
__device__ __forceinline__ unsigned short f2bf(float x) {
    union { float f; uint32_t u; } v; v.f = x;
    uint32_t r = v.u + 0x7fffu + ((v.u >> 16) & 1u);
    return (unsigned short)(r >> 16);
}

// ---------------------------------------------------------------------------
// K0a: Bp[o][j] = bf16(mix_w[o][ ((j&31)<<6) | (j>>5) ])  (shuffle folded into
// mix-weight columns). One block per row o.
// ---------------------------------------------------------------------------
__global__ void k_permute_mixw(const float* __restrict__ W, unsigned short* __restrict__ Bp) {
    __shared__ float row[2112];  // 2048 + pad every 32
    const int t = threadIdx.x;
    const float* src = W + (size_t)blockIdx.x * IN_F;
#pragma unroll
    for (int q = 0; q < 2; ++q) {
        int id4 = q * 256 + t;
        float4 v = *(const float4*)(src + id4 * 4);
        int i = id4 * 4;
        int b = i + (i >> 5);
        row[b] = v.x; row[b + 1] = v.y; row[b + 2] = v.z; row[b + 3] = v.w;
    }
    __syncthreads();
    unsigned short* dst = Bp + (size_t)blockIdx.x * IN_F;
#pragma unroll
    for (int q = 0; q < 8; ++q) {
        int j = q * 256 + t;
        int i = ((j & 31) << 6) | (j >> 5);
        dst[j] = f2bf(row[i + (i >> 5)]);
    }
}

// ---------------------------------------------------------------------------
// K0b: W1T/W2T[g][d][c] = bf16(stage[g*64+c][d])  (transposed so B-operand
// fragments are contiguous 16B). Blocks 0..31 -> stage1, 32..63 -> stage2.
// ---------------------------------------------------------------------------
__global__ void k_transpose_stages(const float* __restrict__ s1, const float* __restrict__ s2,
                                   unsigned short* __restrict__ W1T, unsigned short* __restrict__ W2T) {
    __shared__ float tile[64 * 65];
    const int b = blockIdx.x;
    const float* src = (b < 32 ? s1 : s2) + (size_t)(b & 31) * 4096;
    unsigned short* dst = (b < 32 ? W1T : W2T) + (size_t)(b & 31) * 4096;
    const int t = threadIdx.x;
#pragma unroll
    for (int q = 0; q < 16; ++q) {
        int id = q * 256 + t;
        tile[(id >> 6) * 65 + (id & 63)] = src[id];
    }
    __syncthreads();
#pragma unroll
    for (int q = 0; q < 16; ++q) {
        int id = q * 256 + t;
        int d = id >> 6, c = id & 63;
        dst[id] = f2bf(tile[c * 65 + d]);
    }
}

// ---------------------------------------------------------------------------
// K1: stage1 block-diagonal GEMM.  H[m][g*64+d] = sum_c x[m][g*64+c]*W1[g][c][d]
// 128 tokens x one group per block. Padded LDS rows (72 shorts) -> conflict-free
// ds_read_b128; H stored via LDS round-trip as 16B lanes (was: 2B scalar -> ~200us).
// ---------------------------------------------------------------------------
#define XS_LD 72
__global__ __launch_bounds__(256, 2) void k_stage1(
    const float* __restrict__ X, const unsigned short* __restrict__ W1T,
    unsigned short* __restrict__ H) {
    __shared__ unsigned short Xs[128 * XS_LD];  // 18 KB (Hs reuses this)
    __shared__ unsigned short Ws[64 * XS_LD];   // 9 KB
    const int t = threadIdx.x;
    const int lane = t & 63, wave = t >> 6;
    const int quad = lane >> 4, l16 = lane & 15;
    const int m0 = blockIdx.x * 128;
    const int g = blockIdx.y;

    // stage W1T group g: 64 rows x 64 shorts, explicit 16B loads into padded rows
    const unsigned short* Wg = W1T + g * 4096;
#pragma unroll
    for (int p = 0; p < 2; ++p) {
        int id = p * 256 + t;
        int r = id >> 3, c = id & 7;
        us8 v = *(const us8*)(Wg + r * 64 + c * 8);
        *(us8*)(Ws + r * XS_LD + c * 8) = v;
    }

    // stage X slice (fp32 -> bf16 in regs), padded rows
    const float* Xg = X + (size_t)m0 * IN_F + g * 64;
#pragma unroll
    for (int q = 0; q < 8; ++q) {
        int id = q * 256 + t;
        int r = id >> 4, c4 = id & 15;
        float4 v = *(const float4*)(Xg + (size_t)r * IN_F + c4 * 4);
        us4 b; b.x = f2bf(v.x); b.y = f2bf(v.y); b.z = f2bf(v.z); b.w = f2bf(v.w);
        *(us4*)(Xs + r * XS_LD + c4 * 4) = b;
    }
    __syncthreads();

    f32x4 acc[2][4];
#pragma unroll
    for (int i = 0; i < 2; ++i)
#pragma unroll
        for (int j = 0; j < 4; ++j) acc[i][j] = (f32x4)0.f;

#pragma unroll
    for (int ks = 0; ks < 2; ++ks) {
        bf16x8 af[2], bfr[4];
#pragma unroll
        for (int i = 0; i < 2; ++i)
            af[i] = *(const bf16x8*)(Xs + (wave * 32 + i * 16 + l16) * XS_LD + ks * 32 + quad * 8);
#pragma unroll
        for (int j = 0; j < 4; ++j)
            bfr[j] = *(const bf16x8*)(Ws + (j * 16 + l16) * XS_LD + ks * 32 + quad * 8);
#pragma unroll
        for (int i = 0; i < 2; ++i)
#pragma unroll
            for (int j = 0; j < 4; ++j)
                acc[i][j] = __builtin_amdgcn_mfma_f32_16x16x32_bf16(af[i], bfr[j], acc[i][j], 0, 0, 0);
    }

    // acc -> LDS (C/D layout row=quad*4+r, col=l16) -> coalesced 16B stores
    __syncthreads();
    unsigned short* Hs = Xs;  // 128 x 64 shorts = 16 KB
#pragma unroll
    for (int i = 0; i < 2; ++i)
#pragma unroll
        for (int j = 0; j < 4; ++j)
#pragma unroll
            for (int r = 0; r < 4; ++r)
                Hs[(wave * 32 + i * 16 + quad * 4 + r) * 64 + j * 16 + l16] = f2bf(acc[i][j][r]);
    __syncthreads();
#pragma unroll
    for (int p = 0; p < 4; ++p) {
        int id = p * 256 + t;
        int r = id >> 3, c = id & 7;
        us8 v = *(const us8*)(Hs + r * 64 + c * 8);
        *(us8*)(H + (size_t)(m0 + r) * IN_F + g * 64 + c * 8) = v;
    }
}

// ---------------------------------------------------------------------------
// K2: mix GEMM (M=16384,N=2048,K=2048, A & B [rows][K] bf16) + stage2 fused
// epilogue. XOR-swizzled LDS: slot c of row r holds K-chunk (c ^ (r&7)) ->
// fragment ds_read_b128 goes 16-way -> 2-way conflicts (2-way is free, m136).
// ---------------------------------------------------------------------------
__global__ __launch_bounds__(256, 2) void k_mix_gemm(
    const unsigned short* __restrict__ A, const unsigned short* __restrict__ B,
    const unsigned short* __restrict__ W2T, float* __restrict__ C) {
    __shared__ unsigned short smem[16384];   // As 16KB | Bs 16KB
    unsigned short* As = smem;
    unsigned short* Bs = smem + 8192;
    const int t = threadIdx.x;
    const int lane = t & 63, wave = t >> 6;
    const int quad = lane >> 4, l16 = lane & 15;
    const int mw = wave & 1, nw = wave >> 1;
    const int m0 = blockIdx.x * 128;
    const int n0 = blockIdx.y * 128;
    const int rr = t >> 3, chunk = t & 7;      // 32 rows x 8 16B-chunks per issue
    const int gsw = (chunk ^ (rr & 7)) * 8;    // swizzled global chunk offset (shorts)
    const int lsw = l16 & 7;                   // read-side swizzle key (row&7 == l16&7)

    f32x4 acc[4][4];
#pragma unroll
    for (int i = 0; i < 4; ++i)
#pragma unroll
        for (int j = 0; j < 4; ++j) acc[i][j] = (f32x4)0.f;

    for (int kb = 0; kb < IN_F; kb += 64) {
#pragma unroll
        for (int q = 0; q < 4; ++q) {
            int r = q * 32 + rr;
            async16((char*)As + (size_t)(q * 4096 + t * 16),
                    A + (size_t)(m0 + r) * IN_F + kb + gsw);
            async16((char*)Bs + (size_t)(q * 4096 + t * 16),
                    B + (size_t)(n0 + r) * IN_F + kb + gsw);
        }
        __syncthreads();
#pragma unroll
        for (int ks = 0; ks < 2; ++ks) {
            bf16x8 af[4], bfr[4];
#pragma unroll
            for (int i = 0; i < 4; ++i)
                af[i] = *(const bf16x8*)(As + (mw * 64 + i * 16 + l16) * 64
                                            + (((ks * 4 + quad) ^ lsw) * 8));
#pragma unroll
            for (int j = 0; j < 4; ++j)
                bfr[j] = *(const bf16x8*)(Bs + (nw * 64 + j * 16 + l16) * 64
                                             + (((ks * 4 + quad) ^ lsw) * 8));
#pragma unroll
            for (int i = 0; i < 4; ++i)
#pragma unroll
                for (int j = 0; j < 4; ++j)
                    acc[i][j] = __builtin_amdgcn_mfma_f32_16x16x32_bf16(af[i], bfr[j], acc[i][j], 0, 0, 0);
        }
        __syncthreads();
    }

    // ---- fused stage2 epilogue (P round-trip, same XOR swizzle) ----
    unsigned short* P = smem + wave * 4096;  // 8KB wave-private
#pragma unroll
    for (int i = 0; i < 4; ++i)
#pragma unroll
        for (int j = 0; j < 4; ++j) {
            int cc = j * 2 + (l16 >> 3);     // logical col-chunk
            int ci = l16 & 7;                // short within chunk
#pragma unroll
            for (int r = 0; r < 4; ++r) {
                int pr = i * 16 + quad * 4 + r;
                P[pr * 64 + ((cc ^ (pr & 7)) * 8) + ci] = f2bf(acc[i][j][r]);
            }
        }

    const int g = (n0 >> 6) + nw;
    const unsigned short* W2g = W2T + g * 4096;   // [d][c] bf16, L2-resident
    bf16x8 wb[4][2];
#pragma unroll
    for (int j = 0; j < 4; ++j)
#pragma unroll
        for (int ks = 0; ks < 2; ++ks)
            wb[j][ks] = *(const bf16x8*)(W2g + (j * 16 + l16) * 64 + ks * 32 + quad * 8);

#pragma unroll
    for (int i = 0; i < 4; ++i) {
        bf16x8 pa0 = *(const bf16x8*)(P + (i * 16 + l16) * 64 + ((quad ^ lsw) * 8));
        bf16x8 pa1 = *(const bf16x8*)(P + (i * 16 + l16) * 64 + (((4 + quad) ^ lsw) * 8));
#pragma unroll
        for (int j = 0; j < 4; ++j) {
            f32x4 o = (f32x4)0.f;
            o = __builtin_amdgcn_mfma_f32_16x16x32_bf16(pa0, wb[j][0], o, 0, 0, 0);
            o = __builtin_amdgcn_mfma_f32_16x16x32_bf16(pa1, wb[j][1], o, 0, 0, 0);
            float* Cp = C + (size_t)(m0 + mw * 64 + i * 16 + quad * 4) * OUT_F
                          + (n0 + nw * 64 + j * 16 + l16);
#pragma unroll
            for (int r = 0; r < 4; ++r) Cp[(size_t)r * OUT_F] = o[r];
        }
    }
}

// ---------------------------------------------------------------------------
extern "C" void kernel_launch(void* const* d_in, const int* in_sizes, int n_in,
                              void* d_out, int out_size, void* d_ws, size_t ws_size,
                              hipStream_t stream) {
    const float* x  = (const float*)d_in[0];
    const float* s1 = (const float*)d_in[1];
    const float* s2 = (const float*)d_in[2];
    const float* mw = (const float*)d_in[3];
    float* out = (float*)d_out;

    char* ws = (char*)d_ws;
    unsigned short* hA  = (unsigned short*)ws;                                   // 64 MB
    unsigned short* Bp  = (unsigned short*)(ws + (size_t)MTOK * IN_F * 2);       // 8 MB
    unsigned short* W1T = (unsigned short*)(ws + (size_t)MTOK * IN_F * 2
                                               + (size_t)OUT_F * IN_F * 2);      // 256 KB
    unsigned short* W2T = W1T + 32 * 4096;                                       // 256 KB

    k_permute_mixw<<<2048, 256, 0, stream>>>(mw, Bp);
    k_transpose_stages<<<64, 256, 0, stream>>>(s1, s2, W1T, W2T);
    k_stage1<<<dim3(128, 32), 256, 0, stream>>>(x, W1T, hA);
    k_mix_gemm<<<dim3(128, 16), 256, 0, stream>>>(hA, Bp, W2T, out);
}

// Round 3
// 393.030 us; speedup vs baseline: 1.1053x; 1.0176x over previous
//
#include <hip/hip_runtime.h>
#include <stdint.h>

#define IN_F 2048
#define OUT_F 2048
#define MTOK 16384   // 4 * 4096 tokens

typedef __attribute__((ext_vector_type(8))) __bf16 bf16x8;
typedef __attribute__((ext_vector_type(4))) float f32x4;
typedef __attribute__((ext_vector_type(4))) unsigned short us4;
typedef __attribute__((ext_vector_type(8))) unsigned short us8;

typedef const __attribute__((address_space(1))) void g_void;
typedef __attribute__((address_space(3))) void l_void;

// 16B async global->LDS. LDS dest is wave-uniform base + lane*16 (no padding
// possible on the LDS side -> XOR-swizzle on the GLOBAL-source side).
__device__ __forceinline__ void async16(void* lds, const void* g) {
    __builtin_amdgcn_global_load_lds((g_void*)(uintptr_t)g, (l_void*)(uintptr_t)lds, 16, 0, 0);
}

// fp32 -> bf16 round-to-nearest-even
__device__ __forceinline__ unsigned short f2bf(float x) {
    union { float f; uint32_t u; } v; v.f = x;
    uint32_t r = v.u + 0x7fffu + ((v.u >> 16) & 1u);
    return (unsigned short)(r >> 16);
}

// 8 contiguous fp32 -> bf16x8 fragment (in registers, no LDS round-trip)
__device__ __forceinline__ bf16x8 f8_to_bf8(const float* __restrict__ p) {
    float4 a = *(const float4*)p;
    float4 b = *(const float4*)(p + 4);
    union { us8 u; bf16x8 h; } r;
    r.u[0] = f2bf(a.x); r.u[1] = f2bf(a.y); r.u[2] = f2bf(a.z); r.u[3] = f2bf(a.w);
    r.u[4] = f2bf(b.x); r.u[5] = f2bf(b.y); r.u[6] = f2bf(b.z); r.u[7] = f2bf(b.w);
    return r.h;
}

// ---------------------------------------------------------------------------
// K0: prep. Blocks 0..2047: Bp[o][j] = bf16(mix_w[o][((j&31)<<6)|(j>>5)])
// (shuffle folded into mix-weight columns). Blocks 2048..2111: W1T/W2T[g][d][c]
// = bf16(stage[g*64+c][d]) (transposed for contiguous B-fragments).
// ---------------------------------------------------------------------------
__global__ void k_prep(const float* __restrict__ W,
                       const float* __restrict__ s1, const float* __restrict__ s2,
                       unsigned short* __restrict__ Bp,
                       unsigned short* __restrict__ W1T, unsigned short* __restrict__ W2T) {
    __shared__ float buf[64 * 65];
    const int t = threadIdx.x;
    if (blockIdx.x < 2048) {
        const float* src = W + (size_t)blockIdx.x * IN_F;
#pragma unroll
        for (int q = 0; q < 2; ++q) {
            int id4 = q * 256 + t;
            float4 v = *(const float4*)(src + id4 * 4);
            int i = id4 * 4;
            int b = i + (i >> 5);               // pad every 32 -> conflict-free
            buf[b] = v.x; buf[b + 1] = v.y; buf[b + 2] = v.z; buf[b + 3] = v.w;
        }
        __syncthreads();
        unsigned short* dst = Bp + (size_t)blockIdx.x * IN_F;
#pragma unroll
        for (int q = 0; q < 8; ++q) {
            int j = q * 256 + t;
            int i = ((j & 31) << 6) | (j >> 5);
            dst[j] = f2bf(buf[i + (i >> 5)]);
        }
    } else {
        const int b = blockIdx.x - 2048;
        const float* src = (b < 32 ? s1 : s2) + (size_t)(b & 31) * 4096;
        unsigned short* dst = (b < 32 ? W1T : W2T) + (size_t)(b & 31) * 4096;
#pragma unroll
        for (int q = 0; q < 16; ++q) {
            int id = q * 256 + t;
            buf[(id >> 6) * 65 + (id & 63)] = src[id];
        }
        __syncthreads();
#pragma unroll
        for (int q = 0; q < 16; ++q) {
            int id = q * 256 + t;
            int d = id >> 6, c = id & 63;
            dst[id] = f2bf(buf[c * 65 + d]);
        }
    }
}

// ---------------------------------------------------------------------------
// K1: stage1 block-diagonal GEMM, staging-free.
// H[m][g*64+d] = sum_c x[m][g*64+c]*W1[g][c][d].
// A-fragments: direct global fp32 loads (32B contiguous per lane) + in-reg
// f2bf. W-fragments: direct 16B loads, L2-hot (same 8KB for 128 blocks).
// No input LDS, no pre-barrier; LDS only for the coalescing store transpose.
// ---------------------------------------------------------------------------
#define HS_LD 72   // pad 64->72 shorts: 144B rows, 16B-aligned, spreads banks
__global__ __launch_bounds__(256, 4) void k_stage1(
    const float* __restrict__ X, const unsigned short* __restrict__ W1T,
    unsigned short* __restrict__ H) {
    __shared__ unsigned short Hs[128 * HS_LD];   // 18 KB
    const int t = threadIdx.x;
    const int lane = t & 63, wave = t >> 6;
    const int quad = lane >> 4, l16 = lane & 15;
    const int m0 = blockIdx.x * 128;
    const int g = blockIdx.y;

    // B-fragments: B[n=l16][k=quad*8+j] = W1T[g][n][k]
    const unsigned short* Wg = W1T + g * 4096;
    bf16x8 wf[4][2];
#pragma unroll
    for (int j = 0; j < 4; ++j)
#pragma unroll
        for (int ks = 0; ks < 2; ++ks)
            wf[j][ks] = *(const bf16x8*)(Wg + (j * 16 + l16) * 64 + ks * 32 + quad * 8);

    // A-fragments: A[m=l16][k=quad*8+j] from X rows, direct
    bf16x8 af[2][2];
#pragma unroll
    for (int i = 0; i < 2; ++i)
#pragma unroll
        for (int ks = 0; ks < 2; ++ks)
            af[i][ks] = f8_to_bf8(X + (size_t)(m0 + wave * 32 + i * 16 + l16) * IN_F
                                    + g * 64 + ks * 32 + quad * 8);

    f32x4 acc[2][4];
#pragma unroll
    for (int i = 0; i < 2; ++i)
#pragma unroll
        for (int j = 0; j < 4; ++j) acc[i][j] = (f32x4)0.f;

#pragma unroll
    for (int ks = 0; ks < 2; ++ks)
#pragma unroll
        for (int i = 0; i < 2; ++i)
#pragma unroll
            for (int j = 0; j < 4; ++j)
                acc[i][j] = __builtin_amdgcn_mfma_f32_16x16x32_bf16(af[i][ks], wf[j][ks], acc[i][j], 0, 0, 0);

    // acc (C/D layout: row=quad*4+r, col=l16) -> padded LDS -> 16B stores
#pragma unroll
    for (int i = 0; i < 2; ++i)
#pragma unroll
        for (int j = 0; j < 4; ++j)
#pragma unroll
            for (int r = 0; r < 4; ++r)
                Hs[(wave * 32 + i * 16 + quad * 4 + r) * HS_LD + j * 16 + l16] = f2bf(acc[i][j][r]);
    __syncthreads();
#pragma unroll
    for (int p = 0; p < 4; ++p) {
        int id = p * 256 + t;
        int r = id >> 3, c = id & 7;
        us8 v = *(const us8*)(Hs + r * HS_LD + c * 8);
        *(us8*)(H + (size_t)(m0 + r) * IN_F + g * 64 + c * 8) = v;
    }
}

// ---------------------------------------------------------------------------
// K2: mix GEMM (M=16384,N=2048,K=2048, A & B [rows][K] bf16) + stage2 fused
// epilogue. XOR-swizzled LDS (slot c of row r holds K-chunk c^(r&7)) -> 0
// bank conflicts (verified R2). Temporal block remap: 16 consecutive blocks
// share one A m-strip -> L2/L3 reuse of A rows.
// ---------------------------------------------------------------------------
__global__ __launch_bounds__(256, 2) void k_mix_gemm(
    const unsigned short* __restrict__ A, const unsigned short* __restrict__ B,
    const unsigned short* __restrict__ W2T, float* __restrict__ C) {
    __shared__ unsigned short smem[16384];   // As 16KB | Bs 16KB
    unsigned short* As = smem;
    unsigned short* Bs = smem + 8192;
    const int t = threadIdx.x;
    const int lane = t & 63, wave = t >> 6;
    const int quad = lane >> 4, l16 = lane & 15;
    const int mw = wave & 1, nw = wave >> 1;
    // temporal remap: dispatch is x-fastest; lin..lin+15 = one m-strip x all n
    const int lin = blockIdx.y * 128 + blockIdx.x;
    const int m0 = (lin >> 4) * 128;
    const int n0 = (lin & 15) * 128;
    const int rr = t >> 3, chunk = t & 7;      // 32 rows x 8 16B-chunks per issue
    const int gsw = (chunk ^ (rr & 7)) * 8;    // swizzled source chunk (shorts)
    const int lsw = l16 & 7;                   // read-side swizzle key

    f32x4 acc[4][4];
#pragma unroll
    for (int i = 0; i < 4; ++i)
#pragma unroll
        for (int j = 0; j < 4; ++j) acc[i][j] = (f32x4)0.f;

    for (int kb = 0; kb < IN_F; kb += 64) {
#pragma unroll
        for (int q = 0; q < 4; ++q) {
            int r = q * 32 + rr;
            async16((char*)As + (size_t)(q * 4096 + t * 16),
                    A + (size_t)(m0 + r) * IN_F + kb + gsw);
            async16((char*)Bs + (size_t)(q * 4096 + t * 16),
                    B + (size_t)(n0 + r) * IN_F + kb + gsw);
        }
        __syncthreads();
#pragma unroll
        for (int ks = 0; ks < 2; ++ks) {
            bf16x8 af[4], bfr[4];
#pragma unroll
            for (int i = 0; i < 4; ++i)
                af[i] = *(const bf16x8*)(As + (mw * 64 + i * 16 + l16) * 64
                                            + (((ks * 4 + quad) ^ lsw) * 8));
#pragma unroll
            for (int j = 0; j < 4; ++j)
                bfr[j] = *(const bf16x8*)(Bs + (nw * 64 + j * 16 + l16) * 64
                                             + (((ks * 4 + quad) ^ lsw) * 8));
#pragma unroll
            for (int i = 0; i < 4; ++i)
#pragma unroll
                for (int j = 0; j < 4; ++j)
                    acc[i][j] = __builtin_amdgcn_mfma_f32_16x16x32_bf16(af[i], bfr[j], acc[i][j], 0, 0, 0);
        }
        __syncthreads();
    }

    // ---- fused stage2 epilogue (P round-trip, same XOR swizzle) ----
    unsigned short* P = smem + wave * 4096;  // 8KB wave-private
#pragma unroll
    for (int i = 0; i < 4; ++i)
#pragma unroll
        for (int j = 0; j < 4; ++j) {
            int cc = j * 2 + (l16 >> 3);     // logical col-chunk
            int ci = l16 & 7;                // short within chunk
#pragma unroll
            for (int r = 0; r < 4; ++r) {
                int pr = i * 16 + quad * 4 + r;
                P[pr * 64 + ((cc ^ (pr & 7)) * 8) + ci] = f2bf(acc[i][j][r]);
            }
        }

    const int g = (n0 >> 6) + nw;
    const unsigned short* W2g = W2T + g * 4096;   // [d][c] bf16, L2-resident
    bf16x8 wb[4][2];
#pragma unroll
    for (int j = 0; j < 4; ++j)
#pragma unroll
        for (int ks = 0; ks < 2; ++ks)
            wb[j][ks] = *(const bf16x8*)(W2g + (j * 16 + l16) * 64 + ks * 32 + quad * 8);

#pragma unroll
    for (int i = 0; i < 4; ++i) {
        bf16x8 pa0 = *(const bf16x8*)(P + (i * 16 + l16) * 64 + ((quad ^ lsw) * 8));
        bf16x8 pa1 = *(const bf16x8*)(P + (i * 16 + l16) * 64 + (((4 + quad) ^ lsw) * 8));
#pragma unroll
        for (int j = 0; j < 4; ++j) {
            f32x4 o = (f32x4)0.f;
            o = __builtin_amdgcn_mfma_f32_16x16x32_bf16(pa0, wb[j][0], o, 0, 0, 0);
            o = __builtin_amdgcn_mfma_f32_16x16x32_bf16(pa1, wb[j][1], o, 0, 0, 0);
            float* Cp = C + (size_t)(m0 + mw * 64 + i * 16 + quad * 4) * OUT_F
                          + (n0 + nw * 64 + j * 16 + l16);
#pragma unroll
            for (int r = 0; r < 4; ++r) Cp[(size_t)r * OUT_F] = o[r];
        }
    }
}

// ---------------------------------------------------------------------------
extern "C" void kernel_launch(void* const* d_in, const int* in_sizes, int n_in,
                              void* d_out, int out_size, void* d_ws, size_t ws_size,
                              hipStream_t stream) {
    const float* x  = (const float*)d_in[0];
    const float* s1 = (const float*)d_in[1];
    const float* s2 = (const float*)d_in[2];
    const float* mw = (const float*)d_in[3];
    float* out = (float*)d_out;

    char* ws = (char*)d_ws;
    unsigned short* hA  = (unsigned short*)ws;                                   // 64 MB
    unsigned short* Bp  = (unsigned short*)(ws + (size_t)MTOK * IN_F * 2);       // 8 MB
    unsigned short* W1T = (unsigned short*)(ws + (size_t)MTOK * IN_F * 2
                                               + (size_t)OUT_F * IN_F * 2);      // 256 KB
    unsigned short* W2T = W1T + 32 * 4096;                                       // 256 KB

    k_prep<<<2112, 256, 0, stream>>>(mw, s1, s2, Bp, W1T, W2T);
    k_stage1<<<dim3(128, 32), 256, 0, stream>>>(x, W1T, hA);
    k_mix_gemm<<<dim3(128, 16), 256, 0, stream>>>(hA, Bp, W2T, out);
}